// Round 9
// baseline (18.397 us; speedup 1.0000x reference)
//
#include <hip/hip_runtime.h>
#include <stdint.h>

#define BATCH 2048
#define NPS 8
#define DFEAT 256

// Constant-address-space float: forces s_load (SMEM) codegen for uniform reads.
typedef const float __attribute__((address_space(4))) cfp;
// Address spaces for global_load_lds.
typedef __attribute__((address_space(3))) uint32_t lds_u32;
typedef const __attribute__((address_space(1))) uint32_t glb_u32;

// MAIN KERNEL: byte-identical to round 8 (so dur delta is interpretable).
__global__ __launch_bounds__(512) void ppdet_kernel(
    const float* __restrict__ eq,      // (B, 16, 256)
    const float* __restrict__ r_ei,    // (B, 16, 4, 3)
    const float* __restrict__ W,       // (2, 512, 8)
    const float* __restrict__ bias,    // (2, 8)
    const float* __restrict__ env_dim, // (2, 8, 4, 3, 3)
    const float* __restrict__ env_ion, // (2, 4, 8)
    float* __restrict__ out)           // (2, 2048, 8)
{
    __shared__ __align__(16) float X[4 * 64 * 64]; // 64KB, quarter-major
    __shared__ __align__(16) float AB[64 * 16];    // [row][k<8:A+bias, k>=8:Bt]
    __shared__ __align__(16) float envl[512];      // [w][j][k]
    float* part = X; // 8192 floats = X's Q0+Q1 region, disjoint from Q3 reads

    const int tid = threadIdx.x;
    const int bid = blockIdx.x;
    const int s  = bid & 1;
    const int b0 = (bid >> 1) * 8;

    const int wq   = __builtin_amdgcn_readfirstlane(tid >> 6); // 0..7, uniform
    const int lane = tid & 63;

    // ---- Stage issue: 8 DMAs per wave, strict quarter order.
    {
        const float* gw = eq + ((size_t)(b0 + wq) * 16 + s * 8) * DFEAT;
#pragma unroll
        for (int q = 0; q < 4; ++q) {
#pragma unroll
            for (int u = 0; u < 2; ++u) {
                const int r0 = wq * 8 + u * 4;       // wave-uniform row base
                const int r  = r0 + (lane >> 4);     // row this lane feeds
                const int c  = (lane & 15) ^ ((r >> 1) & 7); // src chunk swizzle
                const float* src = gw + (size_t)(r & 7) * DFEAT + q * 64 + c * 4;
                lds_u32* dst = (lds_u32*)(uintptr_t)&X[q * 4096 + r0 * 64];
                __builtin_amdgcn_global_load_lds((glb_u32*)src, dst, 16, 0, 0);
            }
            __builtin_amdgcn_sched_barrier(0); // pin issue order per quarter
        }
    }

    // ---- GEMM: 4 counted-vmcnt phases. acc persists across quarters.
    float acc[16];
#pragma unroll
    for (int k = 0; k < 16; ++k) acc[k] = 0.f;

    cfp* wbase = (cfp*)(uintptr_t)(W + s * 4096);
    const int perm = (lane >> 1) & 7;

#pragma unroll
    for (int q = 0; q < 4; ++q) {
        if (q == 0)      asm volatile("s_waitcnt vmcnt(6)" ::: "memory");
        else if (q == 1) asm volatile("s_waitcnt vmcnt(4)" ::: "memory");
        else if (q == 2) asm volatile("s_waitcnt vmcnt(2)" ::: "memory");
        else             asm volatile("s_waitcnt vmcnt(0)" ::: "memory");
        __builtin_amdgcn_s_barrier();
        __builtin_amdgcn_sched_barrier(0);

        // lane = row; un-swizzle on read (b128 at the 8-way floor).
        const float4 xa = *(const float4*)
            &X[q * 4096 + lane * 64 + (((2 * wq)     ^ perm) << 2)];
        const float4 xb = *(const float4*)
            &X[q * 4096 + lane * 64 + (((2 * wq + 1) ^ perm) << 2)];
        cfp* w1 = wbase + (q * 64 + wq * 8) * 8; // W1 rows; W2 at +2048
        const float xs[8] = {xa.x, xa.y, xa.z, xa.w, xb.x, xb.y, xb.z, xb.w};
#pragma unroll
        for (int i = 0; i < 8; ++i) {
            const float xc = xs[i];
#pragma unroll
            for (int k = 0; k < 8; ++k) {
                acc[k]     = fmaf(xc, w1[i * 8 + k],        acc[k]);
                acc[8 + k] = fmaf(xc, w1[2048 + i * 8 + k], acc[8 + k]);
            }
        }
    }

    // ---- Part-store (writes X's Q0/Q1 region; Q3 readers untouched).
    {
        float* pb = part + (wq * 64 + lane) * 16;
        const int sw = (lane >> 1) & 3;
#pragma unroll
        for (int kg = 0; kg < 4; ++kg) {
            int slot = kg ^ sw;
            float4 v = make_float4(acc[kg * 4], acc[kg * 4 + 1],
                                   acc[kg * 4 + 2], acc[kg * 4 + 3]);
            *(float4*)(pb + slot * 4) = v;
        }
    }

    // ---- Envelope (VMEM here is after vmcnt(0): counts stayed exact above).
    {
        const int w = tid >> 6, k = (tid >> 3) & 7, j = tid & 7;
        const size_t rrow = ((size_t)(b0 + w) * 16 + s * 8 + j) * 12;
        const float4* rp = (const float4*)(r_ei + rrow);
        float4 ra = rp[0], rb = rp[1], rc = rp[2];
        float rr[12] = {ra.x, ra.y, ra.z, ra.w, rb.x, rb.y, rb.z, rb.w,
                        rc.x, rc.y, rc.z, rc.w};
        float e = 0.f;
#pragma unroll
        for (int a = 0; a < 4; ++a) {
            const float* Md = env_dim + ((size_t)(s * 8 + k) * 4 + a) * 9;
            float r0 = rr[a * 3], r1 = rr[a * 3 + 1], r2 = rr[a * 3 + 2];
            float e0 = r0 * Md[0] + r1 * Md[3] + r2 * Md[6];
            float e1 = r0 * Md[1] + r1 * Md[4] + r2 * Md[7];
            float e2 = r0 * Md[2] + r1 * Md[5] + r2 * Md[8];
            float dist = sqrtf(e0 * e0 + e1 * e1 + e2 * e2);
            e = fmaf(env_ion[(s * 4 + a) * 8 + k], __expf(-dist), e);
        }
        envl[w * 64 + j * 8 + k] = e;
    }

    __syncthreads();

    // ---- Reduce 8 f-subset partials -> AB, fold bias into A half.
    if (tid < 256) {
        const int row = tid >> 2, sl = tid & 3;
        const int g = sl ^ ((row >> 1) & 3); // true k-group held in slot sl
        float4 sum = make_float4(0.f, 0.f, 0.f, 0.f);
#pragma unroll
        for (int q2 = 0; q2 < 8; ++q2) {
            float4 v = *(const float4*)(part + (q2 * 64 + row) * 16 + sl * 4);
            sum.x += v.x; sum.y += v.y; sum.z += v.z; sum.w += v.w;
        }
        if (g < 2) {
            sum.x += bias[s * 8 + g * 4];
            sum.y += bias[s * 8 + g * 4 + 1];
            sum.z += bias[s * 8 + g * 4 + 2];
            sum.w += bias[s * 8 + g * 4 + 3];
        }
        *(float4*)(AB + row * 16 + g * 4) = sum;
    }

    __syncthreads();

    // ---- One 8x8 determinant per thread, in-register LU with partial
    // pivoting; all register indices compile-time constants.
    if (tid < 64) {
        const int w = tid >> 3, i = tid & 7;
        float Arow[8];
#pragma unroll
        for (int k = 0; k < 8; ++k) Arow[k] = AB[(w * 8 + i) * 16 + k];
        float M[8][8];
#pragma unroll
        for (int j = 0; j < 8; ++j) {
#pragma unroll
            for (int k = 0; k < 8; ++k)
                M[j][k] = (Arow[k] + AB[(w * 8 + j) * 16 + 8 + k])
                          * envl[w * 64 + j * 8 + k];
        }
        float det = 1.f;
#pragma unroll
        for (int p = 0; p < 8; ++p) {
            int piv = p;
            float mx = fabsf(M[p][p]);
#pragma unroll
            for (int r2 = p + 1; r2 < 8; ++r2) {
                float v = fabsf(M[r2][p]);
                if (v > mx) { mx = v; piv = r2; }
            }
#pragma unroll
            for (int r2 = p + 1; r2 < 8; ++r2) {
                bool sw = (piv == r2);
#pragma unroll
                for (int c = p; c < 8; ++c) {
                    float a = M[p][c], bb = M[r2][c];
                    M[p][c]  = sw ? bb : a;
                    M[r2][c] = sw ? a : bb;
                }
            }
            det = (piv != p) ? -det : det;
            float d = M[p][p];
            det *= d;
            float inv = (d != 0.f) ? 1.f / d : 0.f;
#pragma unroll
            for (int r2 = p + 1; r2 < 8; ++r2) {
                float fct = M[r2][p] * inv;
#pragma unroll
                for (int c = p + 1; c < 8; ++c) M[r2][c] -= fct * M[p][c];
            }
        }
        out[(size_t)s * (BATCH * NPS) + (size_t)(b0 + w) * NPS + i] = det;
    }
}

// STAGE-ONLY PROBE: identical grid/LDS/DMA pattern as the main kernel's
// staging phase, nothing else. Writes only LDS (no d_out, no d_ws).
// Measures pure staging wall-time: dur_round9 - dur_round8 - launch_gap.
__global__ __launch_bounds__(512) void stage_probe_kernel(
    const float* __restrict__ eq)
{
    __shared__ __align__(16) float X[4 * 64 * 64]; // 64KB -> same 2 blocks/CU

    const int tid = threadIdx.x;
    const int bid = blockIdx.x;
    const int s  = bid & 1;
    const int b0 = (bid >> 1) * 8;
    const int wq   = __builtin_amdgcn_readfirstlane(tid >> 6);
    const int lane = tid & 63;

    const float* gw = eq + ((size_t)(b0 + wq) * 16 + s * 8) * DFEAT;
#pragma unroll
    for (int q = 0; q < 4; ++q) {
#pragma unroll
        for (int u = 0; u < 2; ++u) {
            const int r0 = wq * 8 + u * 4;
            const int r  = r0 + (lane >> 4);
            const int c  = (lane & 15) ^ ((r >> 1) & 7);
            const float* src = gw + (size_t)(r & 7) * DFEAT + q * 64 + c * 4;
            lds_u32* dst = (lds_u32*)(uintptr_t)&X[q * 4096 + r0 * 64];
            __builtin_amdgcn_global_load_lds((glb_u32*)src, dst, 16, 0, 0);
        }
        __builtin_amdgcn_sched_barrier(0);
    }
    asm volatile("s_waitcnt vmcnt(0)" ::: "memory");
}

extern "C" void kernel_launch(void* const* d_in, const int* in_sizes, int n_in,
                              void* d_out, int out_size, void* d_ws, size_t ws_size,
                              hipStream_t stream) {
    const float* eq      = (const float*)d_in[0];
    const float* r_ei    = (const float*)d_in[1];
    const float* W       = (const float*)d_in[2];
    const float* bias    = (const float*)d_in[3];
    const float* env_dim = (const float*)d_in[4];
    const float* env_ion = (const float*)d_in[5];
    float* out = (float*)d_out;

    ppdet_kernel<<<512, 512, 0, stream>>>(eq, r_ei, W, bias, env_dim, env_ion, out);
    // Diagnostic: stage-only probe; dur delta vs round 8 = pure staging time.
    stage_probe_kernel<<<512, 512, 0, stream>>>(eq);
}

// Round 10
// 14.771 us; speedup vs baseline: 1.2455x; 1.2455x over previous
//
#include <hip/hip_runtime.h>
#include <stdint.h>

#define BATCH 2048
#define NPS 8
#define DFEAT 256

// Constant-address-space float: forces s_load (SMEM) codegen for uniform reads.
typedef const float __attribute__((address_space(4))) cfp;
// Address spaces for global_load_lds.
typedef __attribute__((address_space(3))) uint32_t lds_u32;
typedef const __attribute__((address_space(1))) uint32_t glb_u32;

// Block: 512 threads = 8 waves, 8 walkers x 1 spin (64 rows, 64 dets).
// vs r8: (1) ALL env VMEM loads are issued BEFORE the 8 staging DMAs, so they
// are the OLDEST vmcnt entries and the vmcnt(6/4/2/0) gate arithmetic is
// unchanged (FIFO retirement: <=6 outstanding => env-all + 2 DMAs done).
// Env compute runs in the dead window between DMA issue and Q0 arrival.
// (2) LU divide -> v_rcp_f32 (validated r2, absmax 1.9e-6).
__global__ __launch_bounds__(512) void ppdet_kernel(
    const float* __restrict__ eq,      // (B, 16, 256)
    const float* __restrict__ r_ei,    // (B, 16, 4, 3)
    const float* __restrict__ W,       // (2, 512, 8)
    const float* __restrict__ bias,    // (2, 8)
    const float* __restrict__ env_dim, // (2, 8, 4, 3, 3)
    const float* __restrict__ env_ion, // (2, 4, 8)
    float* __restrict__ out)           // (2, 2048, 8)
{
    __shared__ __align__(16) float X[4 * 64 * 64]; // 64KB, quarter-major
    __shared__ __align__(16) float AB[64 * 16];    // [row][k<8:A+bias, k>=8:Bt]
    __shared__ __align__(16) float envl[512];      // [w][j][k]
    float* part = X; // 8192 floats = X's Q0+Q1 region, disjoint from Q3 reads

    const int tid = threadIdx.x;
    const int bid = blockIdx.x;
    const int s  = bid & 1;
    const int b0 = (bid >> 1) * 8;

    const int wq   = __builtin_amdgcn_readfirstlane(tid >> 6); // 0..7, uniform
    const int lane = tid & 63;

    // ---- Env LOADS first (oldest vmcnt entries; keeps gate arithmetic exact)
    const int ew = tid >> 6, ek = (tid >> 3) & 7, ej = tid & 7;
    float4 ra, rb, rc;
    float md[4][9];
    float ei[4];
    {
        const size_t rrow = ((size_t)(b0 + ew) * 16 + s * 8 + ej) * 12;
        const float4* rp = (const float4*)(r_ei + rrow);
        ra = rp[0]; rb = rp[1]; rc = rp[2];
#pragma unroll
        for (int a = 0; a < 4; ++a) {
            const float* Md = env_dim + ((size_t)(s * 8 + ek) * 4 + a) * 9;
            const float4 m0 = *(const float4*)(Md);
            const float4 m1 = *(const float4*)(Md + 4);
            md[a][0] = m0.x; md[a][1] = m0.y; md[a][2] = m0.z; md[a][3] = m0.w;
            md[a][4] = m1.x; md[a][5] = m1.y; md[a][6] = m1.z; md[a][7] = m1.w;
            md[a][8] = Md[8];
            ei[a] = env_ion[(s * 4 + a) * 8 + ek];
        }
    }
    __builtin_amdgcn_sched_barrier(0); // env loads stay ahead of the DMAs

    // ---- Stage issue: 8 DMAs per wave, strict quarter order.
    {
        const float* gw = eq + ((size_t)(b0 + wq) * 16 + s * 8) * DFEAT;
#pragma unroll
        for (int q = 0; q < 4; ++q) {
#pragma unroll
            for (int u = 0; u < 2; ++u) {
                const int r0 = wq * 8 + u * 4;       // wave-uniform row base
                const int r  = r0 + (lane >> 4);     // row this lane feeds
                const int c  = (lane & 15) ^ ((r >> 1) & 7); // src chunk swizzle
                const float* src = gw + (size_t)(r & 7) * DFEAT + q * 64 + c * 4;
                lds_u32* dst = (lds_u32*)(uintptr_t)&X[q * 4096 + r0 * 64];
                __builtin_amdgcn_global_load_lds((glb_u32*)src, dst, 16, 0, 0);
            }
            __builtin_amdgcn_sched_barrier(0); // pin issue order per quarter
        }
    }

    // ---- Env COMPUTE in the DMA-flight window (waits only on env loads:
    // compiler emits vmcnt(8) — the 8 DMAs stay outstanding).
    {
        float rr[12] = {ra.x, ra.y, ra.z, ra.w, rb.x, rb.y, rb.z, rb.w,
                        rc.x, rc.y, rc.z, rc.w};
        float e = 0.f;
#pragma unroll
        for (int a = 0; a < 4; ++a) {
            float r0 = rr[a * 3], r1 = rr[a * 3 + 1], r2 = rr[a * 3 + 2];
            float e0 = r0 * md[a][0] + r1 * md[a][3] + r2 * md[a][6];
            float e1 = r0 * md[a][1] + r1 * md[a][4] + r2 * md[a][7];
            float e2 = r0 * md[a][2] + r1 * md[a][5] + r2 * md[a][8];
            float dist = sqrtf(e0 * e0 + e1 * e1 + e2 * e2);
            e = fmaf(ei[a], __expf(-dist), e);
        }
        envl[ew * 64 + ej * 8 + ek] = e;
    }
    __builtin_amdgcn_sched_barrier(0); // keep env compute ahead of the gates

    // ---- GEMM: 4 counted-vmcnt phases. acc persists across quarters.
    float acc[16];
#pragma unroll
    for (int k = 0; k < 16; ++k) acc[k] = 0.f;

    cfp* wbase = (cfp*)(uintptr_t)(W + s * 4096);
    const int perm = (lane >> 1) & 7;

#pragma unroll
    for (int q = 0; q < 4; ++q) {
        if (q == 0)      asm volatile("s_waitcnt vmcnt(6)" ::: "memory");
        else if (q == 1) asm volatile("s_waitcnt vmcnt(4)" ::: "memory");
        else if (q == 2) asm volatile("s_waitcnt vmcnt(2)" ::: "memory");
        else             asm volatile("s_waitcnt vmcnt(0)" ::: "memory");
        __builtin_amdgcn_s_barrier();
        __builtin_amdgcn_sched_barrier(0);

        // lane = row; un-swizzle on read (b128 at the 8-way floor).
        const float4 xa = *(const float4*)
            &X[q * 4096 + lane * 64 + (((2 * wq)     ^ perm) << 2)];
        const float4 xb = *(const float4*)
            &X[q * 4096 + lane * 64 + (((2 * wq + 1) ^ perm) << 2)];
        cfp* w1 = wbase + (q * 64 + wq * 8) * 8; // W1 rows; W2 at +2048
        const float xs[8] = {xa.x, xa.y, xa.z, xa.w, xb.x, xb.y, xb.z, xb.w};
#pragma unroll
        for (int i = 0; i < 8; ++i) {
            const float xc = xs[i];
#pragma unroll
            for (int k = 0; k < 8; ++k) {
                acc[k]     = fmaf(xc, w1[i * 8 + k],        acc[k]);
                acc[8 + k] = fmaf(xc, w1[2048 + i * 8 + k], acc[8 + k]);
            }
        }
    }

    // ---- Part-store (writes X's Q0/Q1 region; Q3 readers untouched).
    {
        float* pb = part + (wq * 64 + lane) * 16;
        const int sw = (lane >> 1) & 3;
#pragma unroll
        for (int kg = 0; kg < 4; ++kg) {
            int slot = kg ^ sw;
            float4 v = make_float4(acc[kg * 4], acc[kg * 4 + 1],
                                   acc[kg * 4 + 2], acc[kg * 4 + 3]);
            *(float4*)(pb + slot * 4) = v;
        }
    }

    __syncthreads();

    // ---- Reduce 8 f-subset partials -> AB, fold bias into A half.
    if (tid < 256) {
        const int row = tid >> 2, sl = tid & 3;
        const int g = sl ^ ((row >> 1) & 3); // true k-group held in slot sl
        float4 sum = make_float4(0.f, 0.f, 0.f, 0.f);
#pragma unroll
        for (int q2 = 0; q2 < 8; ++q2) {
            float4 v = *(const float4*)(part + (q2 * 64 + row) * 16 + sl * 4);
            sum.x += v.x; sum.y += v.y; sum.z += v.z; sum.w += v.w;
        }
        if (g < 2) {
            sum.x += bias[s * 8 + g * 4];
            sum.y += bias[s * 8 + g * 4 + 1];
            sum.z += bias[s * 8 + g * 4 + 2];
            sum.w += bias[s * 8 + g * 4 + 3];
        }
        *(float4*)(AB + row * 16 + g * 4) = sum;
    }

    __syncthreads();

    // ---- One 8x8 determinant per thread, in-register LU with partial
    // pivoting; all register indices compile-time constants. rcp for the
    // elimination factor (validated r2: absmax 1.9e-6, threshold 6.6e-4).
    if (tid < 64) {
        const int w = tid >> 3, i = tid & 7;
        float Arow[8];
#pragma unroll
        for (int k = 0; k < 8; ++k) Arow[k] = AB[(w * 8 + i) * 16 + k];
        float M[8][8];
#pragma unroll
        for (int j = 0; j < 8; ++j) {
#pragma unroll
            for (int k = 0; k < 8; ++k)
                M[j][k] = (Arow[k] + AB[(w * 8 + j) * 16 + 8 + k])
                          * envl[w * 64 + j * 8 + k];
        }
        float det = 1.f;
#pragma unroll
        for (int p = 0; p < 8; ++p) {
            int piv = p;
            float mx = fabsf(M[p][p]);
#pragma unroll
            for (int r2 = p + 1; r2 < 8; ++r2) {
                float v = fabsf(M[r2][p]);
                if (v > mx) { mx = v; piv = r2; }
            }
#pragma unroll
            for (int r2 = p + 1; r2 < 8; ++r2) {
                bool sw = (piv == r2);
#pragma unroll
                for (int c = p; c < 8; ++c) {
                    float a = M[p][c], bb = M[r2][c];
                    M[p][c]  = sw ? bb : a;
                    M[r2][c] = sw ? a : bb;
                }
            }
            det = (piv != p) ? -det : det;
            float d = M[p][p];
            det *= d;
            float inv = (d != 0.f) ? __builtin_amdgcn_rcpf(d) : 0.f;
#pragma unroll
            for (int r2 = p + 1; r2 < 8; ++r2) {
                float fct = M[r2][p] * inv;
#pragma unroll
                for (int c = p + 1; c < 8; ++c) M[r2][c] -= fct * M[p][c];
            }
        }
        out[(size_t)s * (BATCH * NPS) + (size_t)(b0 + w) * NPS + i] = det;
    }
}

extern "C" void kernel_launch(void* const* d_in, const int* in_sizes, int n_in,
                              void* d_out, int out_size, void* d_ws, size_t ws_size,
                              hipStream_t stream) {
    const float* eq      = (const float*)d_in[0];
    const float* r_ei    = (const float*)d_in[1];
    const float* W       = (const float*)d_in[2];
    const float* bias    = (const float*)d_in[3];
    const float* env_dim = (const float*)d_in[4];
    const float* env_ion = (const float*)d_in[5];
    float* out = (float*)d_out;

    ppdet_kernel<<<512, 512, 0, stream>>>(eq, r_ei, W, bias, env_dim, env_ion, out);
}

// Round 11
// 14.643 us; speedup vs baseline: 1.2564x; 1.0088x over previous
//
#include <hip/hip_runtime.h>
#include <stdint.h>

#define BATCH 2048
#define NPS 8
#define DFEAT 256

// Constant-address-space float: forces s_load (SMEM) codegen for uniform reads.
typedef const float __attribute__((address_space(4))) cfp;
// Address spaces for global_load_lds.
typedef __attribute__((address_space(3))) uint32_t lds_u32;
typedef const __attribute__((address_space(1))) uint32_t glb_u32;

// Block: 512 threads = 8 waves, 8 walkers x 1 spin (64 rows, 64 dets).
// vs r10: (1) BK=128 -- two vmcnt-gated phases (vmcnt(4)/vmcnt(0)) instead of
// four: half the lockstep barrier events, and each phase's 256 fmacs give the
// compiler room to pipeline the W s_load batches. (2) post-gate
// sched_barrier(0) walls removed -- the gates' "memory" clobber still pins
// all memory ops (ds_read can't hoist above, DMA can't sink below), but W
// s_loads for phase 0 can now issue before gate0 and fly during the wait.
__global__ __launch_bounds__(512) void ppdet_kernel(
    const float* __restrict__ eq,      // (B, 16, 256)
    const float* __restrict__ r_ei,    // (B, 16, 4, 3)
    const float* __restrict__ W,       // (2, 512, 8)
    const float* __restrict__ bias,    // (2, 8)
    const float* __restrict__ env_dim, // (2, 8, 4, 3, 3)
    const float* __restrict__ env_ion, // (2, 4, 8)
    float* __restrict__ out)           // (2, 2048, 8)
{
    __shared__ __align__(16) float X[4 * 64 * 64]; // 64KB, quarter-major
    __shared__ __align__(16) float AB[64 * 16];    // [row][k<8:A+bias, k>=8:Bt]
    __shared__ __align__(16) float envl[512];      // [w][j][k]
    float* part = X; // 8192 floats = X's Q0+Q1 region, disjoint from Q2/Q3 reads

    const int tid = threadIdx.x;
    const int bid = blockIdx.x;
    const int s  = bid & 1;
    const int b0 = (bid >> 1) * 8;

    const int wq   = __builtin_amdgcn_readfirstlane(tid >> 6); // 0..7, uniform
    const int lane = tid & 63;

    // ---- Env LOADS first (oldest vmcnt entries; keeps gate arithmetic exact)
    const int ew = tid >> 6, ek = (tid >> 3) & 7, ej = tid & 7;
    float4 ra, rb, rc;
    float md[4][9];
    float ei[4];
    {
        const size_t rrow = ((size_t)(b0 + ew) * 16 + s * 8 + ej) * 12;
        const float4* rp = (const float4*)(r_ei + rrow);
        ra = rp[0]; rb = rp[1]; rc = rp[2];
#pragma unroll
        for (int a = 0; a < 4; ++a) {
            const float* Md = env_dim + ((size_t)(s * 8 + ek) * 4 + a) * 9;
            const float4 m0 = *(const float4*)(Md);
            const float4 m1 = *(const float4*)(Md + 4);
            md[a][0] = m0.x; md[a][1] = m0.y; md[a][2] = m0.z; md[a][3] = m0.w;
            md[a][4] = m1.x; md[a][5] = m1.y; md[a][6] = m1.z; md[a][7] = m1.w;
            md[a][8] = Md[8];
            ei[a] = env_ion[(s * 4 + a) * 8 + ek];
        }
    }
    __builtin_amdgcn_sched_barrier(0); // env loads stay ahead of the DMAs

    // ---- Stage issue: 8 DMAs per wave, strict quarter order (pins keep the
    // FIFO order the gate counts rely on; Q0,Q1 precede Q2,Q3).
    {
        const float* gw = eq + ((size_t)(b0 + wq) * 16 + s * 8) * DFEAT;
#pragma unroll
        for (int q = 0; q < 4; ++q) {
#pragma unroll
            for (int u = 0; u < 2; ++u) {
                const int r0 = wq * 8 + u * 4;       // wave-uniform row base
                const int r  = r0 + (lane >> 4);     // row this lane feeds
                const int c  = (lane & 15) ^ ((r >> 1) & 7); // src chunk swizzle
                const float* src = gw + (size_t)(r & 7) * DFEAT + q * 64 + c * 4;
                lds_u32* dst = (lds_u32*)(uintptr_t)&X[q * 4096 + r0 * 64];
                __builtin_amdgcn_global_load_lds((glb_u32*)src, dst, 16, 0, 0);
            }
            __builtin_amdgcn_sched_barrier(0); // pin issue order per quarter
        }
    }

    // ---- Env COMPUTE in the DMA-flight window (pinned above gate0 by its
    // envl ds_write vs the gates' memory clobber; VALU hides DMA latency).
    {
        float rr[12] = {ra.x, ra.y, ra.z, ra.w, rb.x, rb.y, rb.z, rb.w,
                        rc.x, rc.y, rc.z, rc.w};
        float e = 0.f;
#pragma unroll
        for (int a = 0; a < 4; ++a) {
            float r0 = rr[a * 3], r1 = rr[a * 3 + 1], r2 = rr[a * 3 + 2];
            float e0 = r0 * md[a][0] + r1 * md[a][3] + r2 * md[a][6];
            float e1 = r0 * md[a][1] + r1 * md[a][4] + r2 * md[a][7];
            float e2 = r0 * md[a][2] + r1 * md[a][5] + r2 * md[a][8];
            float dist = sqrtf(e0 * e0 + e1 * e1 + e2 * e2);
            e = fmaf(ei[a], __expf(-dist), e);
        }
        envl[ew * 64 + ej * 8 + ek] = e;
    }

    // ---- GEMM: 2 counted-vmcnt phases (BK=128). acc persists across phases.
    float acc[16];
#pragma unroll
    for (int k = 0; k < 16; ++k) acc[k] = 0.f;

    cfp* wbase = (cfp*)(uintptr_t)(W + s * 4096);
    const int perm = (lane >> 1) & 7;

#pragma unroll
    for (int h = 0; h < 2; ++h) {
        if (h == 0) asm volatile("s_waitcnt vmcnt(4)" ::: "memory");
        else        asm volatile("s_waitcnt vmcnt(0)" ::: "memory");
        __builtin_amdgcn_s_barrier();

#pragma unroll
        for (int qq = 0; qq < 2; ++qq) {
            const int q = h * 2 + qq;
            // lane = row; un-swizzle on read (b128 at the 8-way floor).
            const float4 xa = *(const float4*)
                &X[q * 4096 + lane * 64 + (((2 * wq)     ^ perm) << 2)];
            const float4 xb = *(const float4*)
                &X[q * 4096 + lane * 64 + (((2 * wq + 1) ^ perm) << 2)];
            cfp* w1 = wbase + (q * 64 + wq * 8) * 8; // W1 rows; W2 at +2048
            const float xs[8] = {xa.x, xa.y, xa.z, xa.w, xb.x, xb.y, xb.z, xb.w};
#pragma unroll
            for (int i = 0; i < 8; ++i) {
                const float xc = xs[i];
#pragma unroll
                for (int k = 0; k < 8; ++k) {
                    acc[k]     = fmaf(xc, w1[i * 8 + k],        acc[k]);
                    acc[8 + k] = fmaf(xc, w1[2048 + i * 8 + k], acc[8 + k]);
                }
            }
        }
    }

    // ---- Part-store (writes X's Q0/Q1 region; phase-1 readers use Q2/Q3).
    {
        float* pb = part + (wq * 64 + lane) * 16;
        const int sw = (lane >> 1) & 3;
#pragma unroll
        for (int kg = 0; kg < 4; ++kg) {
            int slot = kg ^ sw;
            float4 v = make_float4(acc[kg * 4], acc[kg * 4 + 1],
                                   acc[kg * 4 + 2], acc[kg * 4 + 3]);
            *(float4*)(pb + slot * 4) = v;
        }
    }

    __syncthreads();

    // ---- Reduce 8 f-subset partials -> AB, fold bias into A half.
    if (tid < 256) {
        const int row = tid >> 2, sl = tid & 3;
        const int g = sl ^ ((row >> 1) & 3); // true k-group held in slot sl
        float4 sum = make_float4(0.f, 0.f, 0.f, 0.f);
#pragma unroll
        for (int q2 = 0; q2 < 8; ++q2) {
            float4 v = *(const float4*)(part + (q2 * 64 + row) * 16 + sl * 4);
            sum.x += v.x; sum.y += v.y; sum.z += v.z; sum.w += v.w;
        }
        if (g < 2) {
            sum.x += bias[s * 8 + g * 4];
            sum.y += bias[s * 8 + g * 4 + 1];
            sum.z += bias[s * 8 + g * 4 + 2];
            sum.w += bias[s * 8 + g * 4 + 3];
        }
        *(float4*)(AB + row * 16 + g * 4) = sum;
    }

    __syncthreads();

    // ---- One 8x8 determinant per thread, in-register LU with partial
    // pivoting; all register indices compile-time constants. rcp for the
    // elimination factor (validated r2/r10: absmax ~1e-6, threshold 6.6e-4).
    if (tid < 64) {
        const int w = tid >> 3, i = tid & 7;
        float Arow[8];
#pragma unroll
        for (int k = 0; k < 8; ++k) Arow[k] = AB[(w * 8 + i) * 16 + k];
        float M[8][8];
#pragma unroll
        for (int j = 0; j < 8; ++j) {
#pragma unroll
            for (int k = 0; k < 8; ++k)
                M[j][k] = (Arow[k] + AB[(w * 8 + j) * 16 + 8 + k])
                          * envl[w * 64 + j * 8 + k];
        }
        float det = 1.f;
#pragma unroll
        for (int p = 0; p < 8; ++p) {
            int piv = p;
            float mx = fabsf(M[p][p]);
#pragma unroll
            for (int r2 = p + 1; r2 < 8; ++r2) {
                float v = fabsf(M[r2][p]);
                if (v > mx) { mx = v; piv = r2; }
            }
#pragma unroll
            for (int r2 = p + 1; r2 < 8; ++r2) {
                bool sw = (piv == r2);
#pragma unroll
                for (int c = p; c < 8; ++c) {
                    float a = M[p][c], bb = M[r2][c];
                    M[p][c]  = sw ? bb : a;
                    M[r2][c] = sw ? a : bb;
                }
            }
            det = (piv != p) ? -det : det;
            float d = M[p][p];
            det *= d;
            float inv = (d != 0.f) ? __builtin_amdgcn_rcpf(d) : 0.f;
#pragma unroll
            for (int r2 = p + 1; r2 < 8; ++r2) {
                float fct = M[r2][p] * inv;
#pragma unroll
                for (int c = p + 1; c < 8; ++c) M[r2][c] -= fct * M[p][c];
            }
        }
        out[(size_t)s * (BATCH * NPS) + (size_t)(b0 + w) * NPS + i] = det;
    }
}

extern "C" void kernel_launch(void* const* d_in, const int* in_sizes, int n_in,
                              void* d_out, int out_size, void* d_ws, size_t ws_size,
                              hipStream_t stream) {
    const float* eq      = (const float*)d_in[0];
    const float* r_ei    = (const float*)d_in[1];
    const float* W       = (const float*)d_in[2];
    const float* bias    = (const float*)d_in[3];
    const float* env_dim = (const float*)d_in[4];
    const float* env_ion = (const float*)d_in[5];
    float* out = (float*)d_out;

    ppdet_kernel<<<512, 512, 0, stream>>>(eq, r_ei, W, bias, env_dim, env_ion, out);
}